// Round 6
// baseline (221.263 us; speedup 1.0000x reference)
//
#include <hip/hip_runtime.h>

typedef __attribute__((ext_vector_type(8))) short bf16x8;
typedef __attribute__((ext_vector_type(4))) float f32x4;

#if __has_builtin(__builtin_amdgcn_exp2f)
#define EXP2F(x) __builtin_amdgcn_exp2f(x)
#else
extern "C" __device__ float __ocml_native_exp2_f32(float);
#define EXP2F(x) __ocml_native_exp2_f32(x)
#endif

// qscale = log2(e) / 32, baked into Q columns of W_qkv
#define QSCALE 0.04508422002778011f
#define NS 2048

__device__ __forceinline__ ushort f32_to_bf16(float f) {
  union { float f; unsigned u; } x; x.f = f;
  unsigned r = x.u + 0x7fffu + ((x.u >> 16) & 1u);
  return (ushort)(r >> 16);
}

// async global->LDS, 16B per lane; lds base must be wave-uniform
__device__ __forceinline__ void load16_to_lds(const void* g, void* l) {
  __builtin_amdgcn_global_load_lds(
      (const __attribute__((address_space(1))) unsigned int*)(
          reinterpret_cast<uintptr_t>(g)),
      (__attribute__((address_space(3))) unsigned int*)(
          reinterpret_cast<uintptr_t>(l)),
      16, 0, 0);
}

// ---------------------------------------------------------------------------
// prep: blocks [0,2048): convert x -> bf16 (8 elems/thread)
//       blocks [2048,5120): transpose W_qkv -> wqkvT [3072][1024], Q cols scaled
// ---------------------------------------------------------------------------
__global__ __launch_bounds__(256) void prep(
    const float* __restrict__ x, const float* __restrict__ Wqkv,
    ushort* __restrict__ xb, ushort* __restrict__ wqkvT)
{
  __shared__ ushort tile[32][33];
  const int bid = blockIdx.x, t = threadIdx.x;
  if (bid < 2048) {
    size_t i = (size_t)bid * 256 + t;
    const float4* p = (const float4*)(x + i * 8);
    float4 a = p[0], b = p[1];
    union { uint4 v; ushort s[8]; } u;
    u.s[0] = f32_to_bf16(a.x); u.s[1] = f32_to_bf16(a.y);
    u.s[2] = f32_to_bf16(a.z); u.s[3] = f32_to_bf16(a.w);
    u.s[4] = f32_to_bf16(b.x); u.s[5] = f32_to_bf16(b.y);
    u.s[6] = f32_to_bf16(b.z); u.s[7] = f32_to_bf16(b.w);
    *(uint4*)(xb + i * 8) = u.v;
  } else {
    int tb = bid - 2048;                 // 96 col-tiles x 32 row-tiles
    int cb = (tb % 96) * 32, rb = (tb / 96) * 32;
    int tx = t & 31, ty = t >> 5;
    float s = (cb + tx) < 1024 ? QSCALE : 1.0f;
#pragma unroll
    for (int k = 0; k < 4; ++k)
      tile[ty + 8 * k][tx] =
          f32_to_bf16(Wqkv[(size_t)(rb + ty + 8 * k) * 3072 + cb + tx] * s);
    __syncthreads();
#pragma unroll
    for (int k = 0; k < 4; ++k)
      wqkvT[(size_t)(cb + ty + 8 * k) * 1024 + rb + tx] = tile[tx][ty + 8 * k];
  }
}

// ---------------------------------------------------------------------------
// transpose + convert (no scale): out[c][r] = bf16(in[r][c])
// ---------------------------------------------------------------------------
__global__ __launch_bounds__(256) void transpose_w(
    const float* __restrict__ in, ushort* __restrict__ out, int R, int C)
{
  __shared__ ushort tile[32][33];
  int t = threadIdx.x, tx = t & 31, ty = t >> 5;
  int rb = blockIdx.y * 32, cb = blockIdx.x * 32;
#pragma unroll
  for (int k = 0; k < 4; ++k)
    tile[ty + 8 * k][tx] = f32_to_bf16(in[(size_t)(rb + ty + 8 * k) * C + cb + tx]);
  __syncthreads();
#pragma unroll
  for (int k = 0; k < 4; ++k)
    out[(size_t)(cb + ty + 8 * k) * R + rb + tx] = tile[tx][ty + 8 * k];
}

// ---------------------------------------------------------------------------
// GEMM: C[M,N] = A[M,K] * Bt[N,K]^T (+ fp32 bias). bf16 in, fp32 accum.
// 128x128 tile, BK=32, global_load_lds staging. TC=float -> fp32 store+bias,
// TC=ushort -> bf16 store.
// ---------------------------------------------------------------------------
template <typename TC>
__global__ __launch_bounds__(256) void gemm_bt(
    const ushort* __restrict__ A, const ushort* __restrict__ Bt,
    const float* __restrict__ bias, TC* __restrict__ C,
    int M, int N, int K)
{
  __shared__ ushort sA[128 * 32];
  __shared__ ushort sB[128 * 32];

  const int t = threadIdx.x;
  const int lane = t & 63, w = t >> 6;
  const int quad = lane >> 4, l16 = lane & 15;
  const int wr = w >> 1, wc = w & 1;
  const int mbase = blockIdx.y * 128, nbase = blockIdx.x * 128;
  const int lrow = lane >> 2, lchunk = (lane & 3) * 8;

  f32x4 acc[4][4];
#pragma unroll
  for (int i = 0; i < 4; ++i)
#pragma unroll
    for (int j = 0; j < 4; ++j)
      acc[i][j] = (f32x4){0.f, 0.f, 0.f, 0.f};

  for (int kb = 0; kb < K; kb += 32) {
    __syncthreads();
#pragma unroll
    for (int r = 0; r < 2; ++r) {
      int rb = w * 32 + r * 16;
      load16_to_lds(&A[(size_t)(mbase + rb + lrow) * K + kb + lchunk], &sA[rb * 32]);
      load16_to_lds(&Bt[(size_t)(nbase + rb + lrow) * K + kb + lchunk], &sB[rb * 32]);
    }
    __syncthreads();

    bf16x8 af[4], bf[4];
#pragma unroll
    for (int mt = 0; mt < 4; ++mt)
      af[mt] = *(const bf16x8*)&sA[(wr * 64 + mt * 16 + l16) * 32 + quad * 8];
#pragma unroll
    for (int nt = 0; nt < 4; ++nt)
      bf[nt] = *(const bf16x8*)&sB[(wc * 64 + nt * 16 + l16) * 32 + quad * 8];
#pragma unroll
    for (int mt = 0; mt < 4; ++mt)
#pragma unroll
      for (int nt = 0; nt < 4; ++nt)
        acc[mt][nt] = __builtin_amdgcn_mfma_f32_16x16x32_bf16(
            af[mt], bf[nt], acc[mt][nt], 0, 0, 0);
  }

#pragma unroll
  for (int mt = 0; mt < 4; ++mt) {
#pragma unroll
    for (int nt = 0; nt < 4; ++nt) {
      int col = nbase + wc * 64 + nt * 16 + l16;
      float bv = bias ? bias[col] : 0.f;
#pragma unroll
      for (int ri = 0; ri < 4; ++ri) {
        int row = mbase + wr * 64 + mt * 16 + quad * 4 + ri;
        float val = acc[mt][nt][ri] + bv;
        if constexpr (__is_same(TC, float))
          C[(size_t)row * N + col] = val;
        else
          C[(size_t)row * N + col] = f32_to_bf16(val);
      }
    }
  }
}

// ---------------------------------------------------------------------------
// Flash attention, S^T formulation, no-max softmax (Q pre-scaled by
// scale*log2e). P transform C-layout -> A-operand via per-wave LDS buffer
// (proven round-4 path; bpermute can't express the permutation in 1x ops).
// l via ones-MFMA. K/V double-buffered via global_load_lds with a single
// barrier per iteration. 4 waves x 32 q-rows = 128-row Q blocks.
// ---------------------------------------------------------------------------
__device__ __forceinline__ void stage_kv(
    const ushort* __restrict__ qk, const ushort* __restrict__ vt,
    ushort* sKb, ushort* sVb, int b, int h, int kvbase,
    int w, int rowK, int csw)
{
#pragma unroll
  for (int g = 0; g < 2; ++g) {
    int rk = w * 16 + g * 8 + rowK;
    load16_to_lds(&qk[((size_t)(b * NS + kvbase + rk)) * 2048 + 1024 + h * 64 + csw],
                  &sKb[(w * 16 + g * 8) * 64]);
    load16_to_lds(&vt[((size_t)(h * 64 + rk)) * 4096 + b * 2048 + kvbase + csw],
                  &sVb[(w * 16 + g * 8) * 64]);
  }
}

__global__ __launch_bounds__(256) void attn_kernel(
    const ushort* __restrict__ qk, const ushort* __restrict__ vt,
    ushort* __restrict__ attn_out)
{
  __shared__ ushort sK[2][64 * 64];  // [kv][d] chunk-swizzled, double-buffered
  __shared__ ushort sV[2][64 * 64];  // [d][kv] chunk-swizzled
  __shared__ ushort sPt[4][32][72];  // per-wave [i][j], +8 pad (16B-aligned rows)

  const int t = threadIdx.x;
  const int lane = t & 63, w = t >> 6;
  const int quad = lane >> 4, l16 = lane & 15;
  const int bh = blockIdx.y, b = bh >> 4, h = bh & 15;
  const int qbase = blockIdx.x * 128;
  const int rowK = lane >> 3;
  const int csw = ((lane & 7) ^ rowK) * 8;
  const int swz = l16 & 7;

  // Q fragments (B-operand): n=l16 -> i, k=quad*8+j -> d
  bf16x8 qf[2][2];
#pragma unroll
  for (int is = 0; is < 2; ++is)
#pragma unroll
    for (int c = 0; c < 2; ++c)
      qf[is][c] = *(const bf16x8*)&qk[
          ((size_t)(b * NS + qbase + w * 32 + is * 16 + l16)) * 2048 +
          h * 64 + c * 32 + quad * 8];

  bf16x8 ones;
  { union { bf16x8 v; ushort s[8]; } ou;
#pragma unroll
    for (int i = 0; i < 8; ++i) ou.s[i] = 0x3F80;
    ones = ou.v; }

  // kb-invariant pattern masks: masked <=> (i-j) % 32 == 0
  unsigned amask[2][4][2];
#pragma unroll
  for (int is = 0; is < 2; ++is)
#pragma unroll
    for (int mt = 0; mt < 4; ++mt)
#pragma unroll
      for (int hf = 0; hf < 2; ++hf) {
        int r0 = hf * 2, r1 = hf * 2 + 1;
        int base = is * 16 + l16 - mt * 16 - quad * 4;
        unsigned m = 0xFFFFFFFFu;
        if (((base - r0) & 31) == 0) m &= 0xFFFF0000u;
        if (((base - r1) & 31) == 0) m &= 0x0000FFFFu;
        amask[is][mt][hf] = m;
      }

  const int ib64 = (qbase + w * 32) >> 6;  // wave-uniform boundary kv-tile

  f32x4 oacc[2][4];
#pragma unroll
  for (int is = 0; is < 2; ++is)
#pragma unroll
    for (int dt = 0; dt < 4; ++dt) oacc[is][dt] = (f32x4){0.f, 0.f, 0.f, 0.f};
  f32x4 lsum[2];
  lsum[0] = (f32x4){0.f, 0.f, 0.f, 0.f};
  lsum[1] = (f32x4){0.f, 0.f, 0.f, 0.f};

  stage_kv(qk, vt, sK[0], sV[0], b, h, 0, w, rowK, csw);

  for (int kb = 0; kb < NS / 64; ++kb) {
    const int cur = kb & 1;
    const int kvbase = kb * 64;
    __syncthreads();  // buf[cur] staged (vmcnt drained); prefetch overlaps compute
    if (kb < NS / 64 - 1)
      stage_kv(qk, vt, sK[cur ^ 1], sV[cur ^ 1], b, h, kvbase + 64, w, rowK, csw);

    const ushort* K = sK[cur];
    const ushort* V = sV[cur];

    // S^T = K Q^T : lane holds j = mt*16 + quad*4 + ri, i = is*16 + l16
    f32x4 st[2][4];
#pragma unroll
    for (int is = 0; is < 2; ++is)
#pragma unroll
      for (int mt = 0; mt < 4; ++mt) st[is][mt] = (f32x4){0.f, 0.f, 0.f, 0.f};
#pragma unroll
    for (int mt = 0; mt < 4; ++mt)
#pragma unroll
      for (int c = 0; c < 2; ++c) {
        bf16x8 kf = *(const bf16x8*)&K[(mt * 16 + l16) * 64 +
                                       (((c * 4 + quad) ^ swz) * 8)];
        st[0][mt] = __builtin_amdgcn_mfma_f32_16x16x32_bf16(
            kf, qf[0][c], st[0][mt], 0, 0, 0);
        st[1][mt] = __builtin_amdgcn_mfma_f32_16x16x32_bf16(
            kf, qf[1][c], st[1][mt], 0, 0, 0);
      }

    // exp2 + mask + pack pairs, write to sPt (C-layout -> A-layout transform)
    if (kb < ib64) {  // fully past diagonal: pattern mask
#pragma unroll
      for (int is = 0; is < 2; ++is)
#pragma unroll
        for (int mt = 0; mt < 4; ++mt) {
          unsigned pb[4];
#pragma unroll
          for (int ri = 0; ri < 4; ++ri) {
            union { float f; unsigned u; } cv;
            cv.f = EXP2F(st[is][mt][ri]);
            pb[ri] = cv.u + 0x8000u;
          }
          unsigned lo = __builtin_amdgcn_perm(pb[1], pb[0], 0x07060302u) &
                        amask[is][mt][0];
          unsigned hi = __builtin_amdgcn_perm(pb[3], pb[2], 0x07060302u) &
                        amask[is][mt][1];
          *(uint2*)&sPt[w][is * 16 + l16][mt * 16 + quad * 4] =
              make_uint2(lo, hi);
        }
    } else if (kb > ib64) {  // above diagonal: no mask
#pragma unroll
      for (int is = 0; is < 2; ++is)
#pragma unroll
        for (int mt = 0; mt < 4; ++mt) {
          unsigned pb[4];
#pragma unroll
          for (int ri = 0; ri < 4; ++ri) {
            union { float f; unsigned u; } cv;
            cv.f = EXP2F(st[is][mt][ri]);
            pb[ri] = cv.u + 0x8000u;
          }
          unsigned lo = __builtin_amdgcn_perm(pb[1], pb[0], 0x07060302u);
          unsigned hi = __builtin_amdgcn_perm(pb[3], pb[2], 0x07060302u);
          *(uint2*)&sPt[w][is * 16 + l16][mt * 16 + quad * 4] =
              make_uint2(lo, hi);
        }
    } else {  // boundary tile: full per-element test
#pragma unroll
      for (int is = 0; is < 2; ++is) {
        int irow = qbase + w * 32 + is * 16 + l16;
#pragma unroll
        for (int mt = 0; mt < 4; ++mt) {
          unsigned pb[4];
#pragma unroll
          for (int ri = 0; ri < 4; ++ri) {
            int j = kvbase + mt * 16 + quad * 4 + ri;
            float p = EXP2F(st[is][mt][ri]);
            unsigned du = (unsigned)(irow - j);
            if ((du & 0x8000001Fu) == 0u) p = 0.f;
            union { float f; unsigned u; } cv; cv.f = p;
            pb[ri] = cv.u + 0x8000u;
          }
          unsigned lo = __builtin_amdgcn_perm(pb[1], pb[0], 0x07060302u);
          unsigned hi = __builtin_amdgcn_perm(pb[3], pb[2], 0x07060302u);
          *(uint2*)&sPt[w][is * 16 + l16][mt * 16 + quad * 4] =
              make_uint2(lo, hi);
        }
      }
    }

    // O += P V ; l += P * ones (P read back in A-operand layout, wave-local)
#pragma unroll
    for (int c2 = 0; c2 < 2; ++c2) {
      bf16x8 vf[4];
#pragma unroll
      for (int dt = 0; dt < 4; ++dt)
        vf[dt] = *(const bf16x8*)&V[(dt * 16 + l16) * 64 +
                                    (((c2 * 4 + quad) ^ swz) * 8)];
#pragma unroll
      for (int is = 0; is < 2; ++is) {
        bf16x8 pf = *(const bf16x8*)&sPt[w][is * 16 + l16][c2 * 32 + quad * 8];
        lsum[is] = __builtin_amdgcn_mfma_f32_16x16x32_bf16(
            pf, ones, lsum[is], 0, 0, 0);
#pragma unroll
        for (int dt = 0; dt < 4; ++dt)
          oacc[is][dt] = __builtin_amdgcn_mfma_f32_16x16x32_bf16(
              pf, vf[dt], oacc[is][dt], 0, 0, 0);
      }
    }
  }

  // epilogue: O / l   (lane holds i = is*16 + quad*4 + ri, d = dt*16 + l16)
#pragma unroll
  for (int is = 0; is < 2; ++is)
#pragma unroll
    for (int ri = 0; ri < 4; ++ri) {
      float inv = __builtin_amdgcn_rcpf(lsum[is][ri]);
      int ig = qbase + w * 32 + is * 16 + quad * 4 + ri;
#pragma unroll
      for (int dt = 0; dt < 4; ++dt)
        attn_out[(size_t)(b * NS + ig) * 1024 + h * 64 + dt * 16 + l16] =
            f32_to_bf16(oacc[is][dt][ri] * inv);
    }
}

// ---------------------------------------------------------------------------
extern "C" void kernel_launch(void* const* d_in, const int* in_sizes, int n_in,
                              void* d_out, int out_size, void* d_ws, size_t ws_size,
                              hipStream_t stream) {
  const float* x    = (const float*)d_in[0];  // [2,2048,1024] fp32
  const float* Wqkv = (const float*)d_in[1];  // [1024,3072]
  const float* Wout = (const float*)d_in[2];  // [1024,1024]
  const float* bout = (const float*)d_in[3];  // [1024]
  float* out = (float*)d_out;                 // [2,2048,1024] fp32

  ushort* qk    = (ushort*)d_ws;                 // 4096*2048 = 16 MB
  ushort* vt    = qk + (size_t)4096 * 2048;      // 1024*4096 = 8 MB
  ushort* xb    = vt + (size_t)1024 * 4096;      // 8 MB (reused as attnb)
  ushort* wqkvT = xb + (size_t)4096 * 1024;      // 3072*1024 = 6 MB
  ushort* attnb = xb;
  ushort* woutT = wqkvT;                         // overlay after gemm_vt

  // prep: x->bf16 + W_qkv^T (Q cols pre-scaled)
  prep<<<2048 + 3072, 256, 0, stream>>>(x, Wqkv, xb, wqkvT);
  // qk = xb @ WqkvT[0:2048]^T  -> [4096][2048] bf16
  gemm_bt<ushort><<<dim3(16, 32), 256, 0, stream>>>(
      xb, wqkvT, nullptr, qk, 4096, 2048, 1024);
  // V^T = WqkvT[2048:3072] @ xb^T -> [1024][4096] bf16 (coalesced)
  gemm_bt<ushort><<<dim3(32, 8), 256, 0, stream>>>(
      wqkvT + (size_t)2048 * 1024, xb, nullptr, vt, 1024, 4096, 1024);
  // W_out^T (into wqkvT space, now dead)
  transpose_w<<<dim3(32, 32), 256, 0, stream>>>(Wout, woutT, 1024, 1024);
  // attention
  attn_kernel<<<dim3(NS / 128, 32), 256, 0, stream>>>(qk, vt, attnb);
  // out = attnb @ WoutT^T + b_out (fp32)
  gemm_bt<float><<<dim3(8, 32), 256, 0, stream>>>(
      attnb, woutT, bout, out, 4096, 1024, 1024);
}

// Round 7
// 196.110 us; speedup vs baseline: 1.1283x; 1.1283x over previous
//
#include <hip/hip_runtime.h>

typedef __attribute__((ext_vector_type(8))) short bf16x8;
typedef __attribute__((ext_vector_type(4))) float f32x4;

#if __has_builtin(__builtin_amdgcn_exp2f)
#define EXP2F(x) __builtin_amdgcn_exp2f(x)
#else
extern "C" __device__ float __ocml_native_exp2_f32(float);
#define EXP2F(x) __ocml_native_exp2_f32(x)
#endif

// qscale = log2(e) / 32, baked into Q columns of W_qkv
#define QSCALE 0.04508422002778011f
#define NS 2048

__device__ __forceinline__ ushort f32_to_bf16(float f) {
  union { float f; unsigned u; } x; x.f = f;
  unsigned r = x.u + 0x7fffu + ((x.u >> 16) & 1u);
  return (ushort)(r >> 16);
}

// pack two f32 -> one dword of two bf16 (lo = f0, hi = f1)
__device__ __forceinline__ unsigned pack_bf16(float f0, float f1) {
#if __has_builtin(__builtin_amdgcn_cvt_pk_bf16_f32)
  auto pr = __builtin_amdgcn_cvt_pk_bf16_f32(f0, f1);
  unsigned u; __builtin_memcpy(&u, &pr, sizeof(u)); return u;
#else
  union { float f; unsigned u; } a, b;
  a.f = f0; b.f = f1;
  return __builtin_amdgcn_perm(b.u + 0x8000u, a.u + 0x8000u, 0x07060302u);
#endif
}

// async global->LDS, 16B per lane; lds base must be wave-uniform
__device__ __forceinline__ void load16_to_lds(const void* g, void* l) {
  __builtin_amdgcn_global_load_lds(
      (const __attribute__((address_space(1))) unsigned int*)(
          reinterpret_cast<uintptr_t>(g)),
      (__attribute__((address_space(3))) unsigned int*)(
          reinterpret_cast<uintptr_t>(l)),
      16, 0, 0);
}

// ---------------------------------------------------------------------------
// prep: blocks [0,2048): convert x -> bf16 (8 elems/thread)
//       blocks [2048,5120): transpose W_qkv -> wqkvT [3072][1024], Q cols scaled
// ---------------------------------------------------------------------------
__global__ __launch_bounds__(256) void prep(
    const float* __restrict__ x, const float* __restrict__ Wqkv,
    ushort* __restrict__ xb, ushort* __restrict__ wqkvT)
{
  __shared__ ushort tile[32][33];
  const int bid = blockIdx.x, t = threadIdx.x;
  if (bid < 2048) {
    size_t i = (size_t)bid * 256 + t;
    const float4* p = (const float4*)(x + i * 8);
    float4 a = p[0], b = p[1];
    union { uint4 v; ushort s[8]; } u;
    u.s[0] = f32_to_bf16(a.x); u.s[1] = f32_to_bf16(a.y);
    u.s[2] = f32_to_bf16(a.z); u.s[3] = f32_to_bf16(a.w);
    u.s[4] = f32_to_bf16(b.x); u.s[5] = f32_to_bf16(b.y);
    u.s[6] = f32_to_bf16(b.z); u.s[7] = f32_to_bf16(b.w);
    *(uint4*)(xb + i * 8) = u.v;
  } else {
    int tb = bid - 2048;                 // 96 col-tiles x 32 row-tiles
    int cb = (tb % 96) * 32, rb = (tb / 96) * 32;
    int tx = t & 31, ty = t >> 5;
    float s = (cb + tx) < 1024 ? QSCALE : 1.0f;
#pragma unroll
    for (int k = 0; k < 4; ++k)
      tile[ty + 8 * k][tx] =
          f32_to_bf16(Wqkv[(size_t)(rb + ty + 8 * k) * 3072 + cb + tx] * s);
    __syncthreads();
#pragma unroll
    for (int k = 0; k < 4; ++k)
      wqkvT[(size_t)(cb + ty + 8 * k) * 1024 + rb + tx] = tile[tx][ty + 8 * k];
  }
}

// ---------------------------------------------------------------------------
// transpose + convert (no scale): out[c][r] = bf16(in[r][c])
// ---------------------------------------------------------------------------
__global__ __launch_bounds__(256) void transpose_w(
    const float* __restrict__ in, ushort* __restrict__ out, int R, int C)
{
  __shared__ ushort tile[32][33];
  int t = threadIdx.x, tx = t & 31, ty = t >> 5;
  int rb = blockIdx.y * 32, cb = blockIdx.x * 32;
#pragma unroll
  for (int k = 0; k < 4; ++k)
    tile[ty + 8 * k][tx] = f32_to_bf16(in[(size_t)(rb + ty + 8 * k) * C + cb + tx]);
  __syncthreads();
#pragma unroll
  for (int k = 0; k < 4; ++k)
    out[(size_t)(cb + ty + 8 * k) * R + rb + tx] = tile[tx][ty + 8 * k];
}

// ---------------------------------------------------------------------------
// GEMM core: C[*,N] tile (mbase,nbase) = A[*,K] * Bt[N,K]^T (+ fp32 bias).
// bf16 in, fp32 accum. 128x128 tile, BK=32, double-buffered global_load_lds
// staging with a single barrier per K-iter (prefetch issued after barrier
// overlaps the compute phase -- critical at 1 block/CU).
// ---------------------------------------------------------------------------
template <typename TC>
__device__ __forceinline__ void gemm_core(
    const ushort* __restrict__ A, const ushort* __restrict__ Bt,
    const float* __restrict__ bias, TC* __restrict__ C,
    int N, int K, int mbase, int nbase,
    ushort* __restrict__ sA0, ushort* __restrict__ sB0,
    ushort* __restrict__ sA1, ushort* __restrict__ sB1)
{
  const int t = threadIdx.x;
  const int lane = t & 63, w = t >> 6;
  const int quad = lane >> 4, l16 = lane & 15;
  const int wr = w >> 1, wc = w & 1;
  const int lrow = lane >> 2, lchunk = (lane & 3) * 8;

  f32x4 acc[4][4];
#pragma unroll
  for (int i = 0; i < 4; ++i)
#pragma unroll
    for (int j = 0; j < 4; ++j)
      acc[i][j] = (f32x4){0.f, 0.f, 0.f, 0.f};

  // prologue: stage kb=0 into buf0
#pragma unroll
  for (int r = 0; r < 2; ++r) {
    int rb = w * 32 + r * 16;
    load16_to_lds(&A[(size_t)(mbase + rb + lrow) * K + lchunk], &sA0[rb * 32]);
    load16_to_lds(&Bt[(size_t)(nbase + rb + lrow) * K + lchunk], &sB0[rb * 32]);
  }

  for (int kb = 0; kb < K; kb += 32) {
    const bool odd = (kb >> 5) & 1;
    ushort* sA = odd ? sA1 : sA0;
    ushort* sB = odd ? sB1 : sB0;
    ushort* pA = odd ? sA0 : sA1;
    ushort* pB = odd ? sB0 : sB1;
    __syncthreads();  // cur buffer staged (vmcnt drained); prefetch overlaps
    if (kb + 32 < K) {
#pragma unroll
      for (int r = 0; r < 2; ++r) {
        int rb = w * 32 + r * 16;
        load16_to_lds(&A[(size_t)(mbase + rb + lrow) * K + kb + 32 + lchunk],
                      &pA[rb * 32]);
        load16_to_lds(&Bt[(size_t)(nbase + rb + lrow) * K + kb + 32 + lchunk],
                      &pB[rb * 32]);
      }
    }

    bf16x8 af[4], bf[4];
#pragma unroll
    for (int mt = 0; mt < 4; ++mt)
      af[mt] = *(const bf16x8*)&sA[(wr * 64 + mt * 16 + l16) * 32 + quad * 8];
#pragma unroll
    for (int nt = 0; nt < 4; ++nt)
      bf[nt] = *(const bf16x8*)&sB[(wc * 64 + nt * 16 + l16) * 32 + quad * 8];
#pragma unroll
    for (int mt = 0; mt < 4; ++mt)
#pragma unroll
      for (int nt = 0; nt < 4; ++nt)
        acc[mt][nt] = __builtin_amdgcn_mfma_f32_16x16x32_bf16(
            af[mt], bf[nt], acc[mt][nt], 0, 0, 0);
  }

#pragma unroll
  for (int mt = 0; mt < 4; ++mt) {
#pragma unroll
    for (int nt = 0; nt < 4; ++nt) {
      int col = nbase + wc * 64 + nt * 16 + l16;
      float bv = bias ? bias[col] : 0.f;
#pragma unroll
      for (int ri = 0; ri < 4; ++ri) {
        int row = mbase + wr * 64 + mt * 16 + quad * 4 + ri;
        float val = acc[mt][nt][ri] + bv;
        if constexpr (__is_same(TC, float))
          C[(size_t)row * N + col] = val;
        else
          C[(size_t)row * N + col] = f32_to_bf16(val);
      }
    }
  }
}

// blocks [0,512): qk = xb @ WqkvT[0:2048]^T       -> [4096][2048] bf16
// blocks [512,768): V^T = WqkvT[2048:] @ xb^T     -> [1024][4096] bf16
__global__ __launch_bounds__(256) void gemm_qkvt(
    const ushort* __restrict__ xb, const ushort* __restrict__ wqkvT,
    ushort* __restrict__ qk, ushort* __restrict__ vtbuf)
{
  __shared__ ushort sA0[128 * 32], sB0[128 * 32];
  __shared__ ushort sA1[128 * 32], sB1[128 * 32];
  const int bid = blockIdx.x;
  if (bid < 512) {
    gemm_core<ushort>(xb, wqkvT, nullptr, qk, 2048, 1024,
                      (bid >> 4) * 128, (bid & 15) * 128, sA0, sB0, sA1, sB1);
  } else {
    const int id = bid - 512;
    gemm_core<ushort>(wqkvT + (size_t)2048 * 1024, xb, nullptr, vtbuf,
                      4096, 1024, (id >> 5) * 128, (id & 31) * 128,
                      sA0, sB0, sA1, sB1);
  }
}

// out = attnb @ WoutT^T + b_out (fp32 store), 256 blocks
__global__ __launch_bounds__(256) void gemm_out(
    const ushort* __restrict__ attnb, const ushort* __restrict__ woutT,
    const float* __restrict__ bias, float* __restrict__ out)
{
  __shared__ ushort sA0[128 * 32], sB0[128 * 32];
  __shared__ ushort sA1[128 * 32], sB1[128 * 32];
  const int bid = blockIdx.x;
  gemm_core<float>(attnb, woutT, bias, out, 1024, 1024,
                   (bid >> 3) * 128, (bid & 7) * 128, sA0, sB0, sA1, sB1);
}

// ---------------------------------------------------------------------------
// Flash attention, S^T formulation, no-max softmax (Q pre-scaled by
// scale*log2e). P transform C-layout -> A-operand via per-wave LDS buffer.
// l via ones-MFMA. K/V double-buffered via global_load_lds, single barrier
// per iteration. 4 waves x 32 q-rows = 128-row Q blocks.
// ---------------------------------------------------------------------------
__device__ __forceinline__ void stage_kv(
    const ushort* __restrict__ qk, const ushort* __restrict__ vt,
    ushort* sKb, ushort* sVb, int b, int h, int kvbase,
    int w, int rowK, int csw)
{
#pragma unroll
  for (int g = 0; g < 2; ++g) {
    int rk = w * 16 + g * 8 + rowK;
    load16_to_lds(&qk[((size_t)(b * NS + kvbase + rk)) * 2048 + 1024 + h * 64 + csw],
                  &sKb[(w * 16 + g * 8) * 64]);
    load16_to_lds(&vt[((size_t)(h * 64 + rk)) * 4096 + b * 2048 + kvbase + csw],
                  &sVb[(w * 16 + g * 8) * 64]);
  }
}

__global__ __launch_bounds__(256) void attn_kernel(
    const ushort* __restrict__ qk, const ushort* __restrict__ vt,
    ushort* __restrict__ attn_out)
{
  __shared__ ushort sK[2][64 * 64];  // [kv][d] chunk-swizzled, double-buffered
  __shared__ ushort sV[2][64 * 64];  // [d][kv] chunk-swizzled
  __shared__ ushort sPt[4][32][72];  // per-wave [i][j], +8 pad

  const int t = threadIdx.x;
  const int lane = t & 63, w = t >> 6;
  const int quad = lane >> 4, l16 = lane & 15;
  const int bh = blockIdx.y, b = bh >> 4, h = bh & 15;
  const int qbase = blockIdx.x * 128;
  const int rowK = lane >> 3;
  const int csw = ((lane & 7) ^ rowK) * 8;
  const int swz = l16 & 7;

  // Q fragments (B-operand): n=l16 -> i, k=quad*8+j -> d
  bf16x8 qf[2][2];
#pragma unroll
  for (int is = 0; is < 2; ++is)
#pragma unroll
    for (int c = 0; c < 2; ++c)
      qf[is][c] = *(const bf16x8*)&qk[
          ((size_t)(b * NS + qbase + w * 32 + is * 16 + l16)) * 2048 +
          h * 64 + c * 32 + quad * 8];

  bf16x8 ones;
  { union { bf16x8 v; ushort s[8]; } ou;
#pragma unroll
    for (int i = 0; i < 8; ++i) ou.s[i] = 0x3F80;
    ones = ou.v; }

  // kb-invariant pattern masks: masked <=> (i-j) % 32 == 0
  unsigned amask[2][4][2];
#pragma unroll
  for (int is = 0; is < 2; ++is)
#pragma unroll
    for (int mt = 0; mt < 4; ++mt)
#pragma unroll
      for (int hf = 0; hf < 2; ++hf) {
        int r0 = hf * 2, r1 = hf * 2 + 1;
        int base = is * 16 + l16 - mt * 16 - quad * 4;
        unsigned m = 0xFFFFFFFFu;
        if (((base - r0) & 31) == 0) m &= 0xFFFF0000u;
        if (((base - r1) & 31) == 0) m &= 0x0000FFFFu;
        amask[is][mt][hf] = m;
      }

  const int ib64 = (qbase + w * 32) >> 6;  // wave-uniform boundary kv-tile

  f32x4 oacc[2][4];
#pragma unroll
  for (int is = 0; is < 2; ++is)
#pragma unroll
    for (int dt = 0; dt < 4; ++dt) oacc[is][dt] = (f32x4){0.f, 0.f, 0.f, 0.f};
  f32x4 lsum[2];
  lsum[0] = (f32x4){0.f, 0.f, 0.f, 0.f};
  lsum[1] = (f32x4){0.f, 0.f, 0.f, 0.f};

  stage_kv(qk, vt, sK[0], sV[0], b, h, 0, w, rowK, csw);

  for (int kb = 0; kb < NS / 64; ++kb) {
    const int cur = kb & 1;
    const int kvbase = kb * 64;
    __syncthreads();  // buf[cur] staged; prefetch below overlaps compute
    if (kb < NS / 64 - 1)
      stage_kv(qk, vt, sK[cur ^ 1], sV[cur ^ 1], b, h, kvbase + 64, w, rowK, csw);

    const ushort* K = sK[cur];
    const ushort* V = sV[cur];

    // S^T = K Q^T : lane holds j = mt*16 + quad*4 + ri, i = is*16 + l16
    f32x4 st[2][4];
#pragma unroll
    for (int is = 0; is < 2; ++is)
#pragma unroll
      for (int mt = 0; mt < 4; ++mt) st[is][mt] = (f32x4){0.f, 0.f, 0.f, 0.f};
#pragma unroll
    for (int mt = 0; mt < 4; ++mt)
#pragma unroll
      for (int c = 0; c < 2; ++c) {
        bf16x8 kf = *(const bf16x8*)&K[(mt * 16 + l16) * 64 +
                                       (((c * 4 + quad) ^ swz) * 8)];
        st[0][mt] = __builtin_amdgcn_mfma_f32_16x16x32_bf16(
            kf, qf[0][c], st[0][mt], 0, 0, 0);
        st[1][mt] = __builtin_amdgcn_mfma_f32_16x16x32_bf16(
            kf, qf[1][c], st[1][mt], 0, 0, 0);
      }

    // exp2 + mask + pack pairs, write to sPt (C-layout -> A-layout transform)
    if (kb < ib64) {  // fully past diagonal: pattern mask
#pragma unroll
      for (int is = 0; is < 2; ++is)
#pragma unroll
        for (int mt = 0; mt < 4; ++mt) {
          unsigned lo = pack_bf16(EXP2F(st[is][mt][0]), EXP2F(st[is][mt][1])) &
                        amask[is][mt][0];
          unsigned hi = pack_bf16(EXP2F(st[is][mt][2]), EXP2F(st[is][mt][3])) &
                        amask[is][mt][1];
          *(uint2*)&sPt[w][is * 16 + l16][mt * 16 + quad * 4] =
              make_uint2(lo, hi);
        }
    } else if (kb > ib64) {  // above diagonal: no mask
#pragma unroll
      for (int is = 0; is < 2; ++is)
#pragma unroll
        for (int mt = 0; mt < 4; ++mt) {
          unsigned lo = pack_bf16(EXP2F(st[is][mt][0]), EXP2F(st[is][mt][1]));
          unsigned hi = pack_bf16(EXP2F(st[is][mt][2]), EXP2F(st[is][mt][3]));
          *(uint2*)&sPt[w][is * 16 + l16][mt * 16 + quad * 4] =
              make_uint2(lo, hi);
        }
    } else {  // boundary tile: full per-element test
#pragma unroll
      for (int is = 0; is < 2; ++is) {
        int irow = qbase + w * 32 + is * 16 + l16;
#pragma unroll
        for (int mt = 0; mt < 4; ++mt) {
          float p[4];
#pragma unroll
          for (int ri = 0; ri < 4; ++ri) {
            int j = kvbase + mt * 16 + quad * 4 + ri;
            p[ri] = EXP2F(st[is][mt][ri]);
            unsigned du = (unsigned)(irow - j);
            if ((du & 0x8000001Fu) == 0u) p[ri] = 0.f;
          }
          unsigned lo = pack_bf16(p[0], p[1]);
          unsigned hi = pack_bf16(p[2], p[3]);
          *(uint2*)&sPt[w][is * 16 + l16][mt * 16 + quad * 4] =
              make_uint2(lo, hi);
        }
      }
    }

    // O += P V ; l += P * ones (P read back in A-operand layout, wave-local)
#pragma unroll
    for (int c2 = 0; c2 < 2; ++c2) {
      bf16x8 vf[4];
#pragma unroll
      for (int dt = 0; dt < 4; ++dt)
        vf[dt] = *(const bf16x8*)&V[(dt * 16 + l16) * 64 +
                                    (((c2 * 4 + quad) ^ swz) * 8)];
#pragma unroll
      for (int is = 0; is < 2; ++is) {
        bf16x8 pf = *(const bf16x8*)&sPt[w][is * 16 + l16][c2 * 32 + quad * 8];
        lsum[is] = __builtin_amdgcn_mfma_f32_16x16x32_bf16(
            pf, ones, lsum[is], 0, 0, 0);
#pragma unroll
        for (int dt = 0; dt < 4; ++dt)
          oacc[is][dt] = __builtin_amdgcn_mfma_f32_16x16x32_bf16(
              pf, vf[dt], oacc[is][dt], 0, 0, 0);
      }
    }
  }

  // epilogue: O / l   (lane holds i = is*16 + quad*4 + ri, d = dt*16 + l16)
#pragma unroll
  for (int is = 0; is < 2; ++is)
#pragma unroll
    for (int ri = 0; ri < 4; ++ri) {
      float inv = __builtin_amdgcn_rcpf(lsum[is][ri]);
      int ig = qbase + w * 32 + is * 16 + quad * 4 + ri;
#pragma unroll
      for (int dt = 0; dt < 4; ++dt)
        attn_out[(size_t)(b * NS + ig) * 1024 + h * 64 + dt * 16 + l16] =
            f32_to_bf16(oacc[is][dt][ri] * inv);
    }
}

// ---------------------------------------------------------------------------
extern "C" void kernel_launch(void* const* d_in, const int* in_sizes, int n_in,
                              void* d_out, int out_size, void* d_ws, size_t ws_size,
                              hipStream_t stream) {
  const float* x    = (const float*)d_in[0];  // [2,2048,1024] fp32
  const float* Wqkv = (const float*)d_in[1];  // [1024,3072]
  const float* Wout = (const float*)d_in[2];  // [1024,1024]
  const float* bout = (const float*)d_in[3];  // [1024]
  float* out = (float*)d_out;                 // [2,2048,1024] fp32

  ushort* qk    = (ushort*)d_ws;                 // 4096*2048 = 16 MiB
  ushort* vt    = qk + (size_t)4096 * 2048;      // 1024*4096 = 8 MiB
  ushort* xb    = vt + (size_t)1024 * 4096;      // 8 MiB (reused as attnb)
  ushort* wqkvT = xb + (size_t)4096 * 1024;      // 3072*1024 = 6 MiB
  ushort* attnb = xb;
  ushort* woutT = wqkvT;                         // overlay after gemm_qkvt

  // prep: x->bf16 + W_qkv^T (Q cols pre-scaled)
  prep<<<2048 + 3072, 256, 0, stream>>>(x, Wqkv, xb, wqkvT);
  // qk [4096][2048] + V^T [1024][4096], one launch (768 blocks)
  gemm_qkvt<<<768, 256, 0, stream>>>(xb, wqkvT, qk, vt);
  // W_out^T (into wqkvT space, now dead)
  transpose_w<<<dim3(32, 32), 256, 0, stream>>>(Wout, woutT, 1024, 1024);
  // attention
  attn_kernel<<<dim3(NS / 128, 32), 256, 0, stream>>>(qk, vt, attnb);
  // out = attnb @ WoutT^T + b_out (fp32)
  gemm_out<<<256, 256, 0, stream>>>(attnb, woutT, bout, out);
}

// Round 8
// 188.260 us; speedup vs baseline: 1.1753x; 1.0417x over previous
//
#include <hip/hip_runtime.h>

typedef __attribute__((ext_vector_type(8))) short bf16x8;
typedef __attribute__((ext_vector_type(4))) float f32x4;

#if __has_builtin(__builtin_amdgcn_exp2f)
#define EXP2F(x) __builtin_amdgcn_exp2f(x)
#else
extern "C" __device__ float __ocml_native_exp2_f32(float);
#define EXP2F(x) __ocml_native_exp2_f32(x)
#endif

// qscale = log2(e) / 32, baked into Q columns of W_qkv
#define QSCALE 0.04508422002778011f
#define NS 2048

__device__ __forceinline__ ushort f32_to_bf16(float f) {
  union { float f; unsigned u; } x; x.f = f;
  unsigned r = x.u + 0x7fffu + ((x.u >> 16) & 1u);
  return (ushort)(r >> 16);
}

// pack two f32 -> one dword of two bf16 (lo = f0, hi = f1)
__device__ __forceinline__ unsigned pack_bf16(float f0, float f1) {
  union { float f; unsigned u; } a, b;
  a.f = f0; b.f = f1;
  return __builtin_amdgcn_perm(b.u + 0x8000u, a.u + 0x8000u, 0x07060302u);
}

// async global->LDS, 16B per lane; lds base must be wave-uniform
__device__ __forceinline__ void load16_to_lds(const void* g, void* l) {
  __builtin_amdgcn_global_load_lds(
      (const __attribute__((address_space(1))) unsigned int*)(
          reinterpret_cast<uintptr_t>(g)),
      (__attribute__((address_space(3))) unsigned int*)(
          reinterpret_cast<uintptr_t>(l)),
      16, 0, 0);
}

// ---------------------------------------------------------------------------
// prep: blocks [0,2048): convert x -> bf16 (8 elems/thread)
//       blocks [2048,5120): W_qkv^T -> wqkvT [3072][1024], Q cols scaled
//       blocks [5120,6144): W_out^T -> woutT [1024][1024]
// ---------------------------------------------------------------------------
__global__ __launch_bounds__(256) void prep(
    const float* __restrict__ x, const float* __restrict__ Wqkv,
    const float* __restrict__ Wout,
    ushort* __restrict__ xb, ushort* __restrict__ wqkvT,
    ushort* __restrict__ woutT)
{
  __shared__ ushort tile[32][33];
  const int bid = blockIdx.x, t = threadIdx.x;
  if (bid < 2048) {
    size_t i = (size_t)bid * 256 + t;
    const float4* p = (const float4*)(x + i * 8);
    float4 a = p[0], b = p[1];
    union { uint4 v; ushort s[8]; } u;
    u.s[0] = f32_to_bf16(a.x); u.s[1] = f32_to_bf16(a.y);
    u.s[2] = f32_to_bf16(a.z); u.s[3] = f32_to_bf16(a.w);
    u.s[4] = f32_to_bf16(b.x); u.s[5] = f32_to_bf16(b.y);
    u.s[6] = f32_to_bf16(b.z); u.s[7] = f32_to_bf16(b.w);
    *(uint4*)(xb + i * 8) = u.v;
  } else if (bid < 5120) {
    int tb = bid - 2048;                 // 96 col-tiles x 32 row-tiles
    int cb = (tb % 96) * 32, rb = (tb / 96) * 32;
    int tx = t & 31, ty = t >> 5;
    float s = (cb + tx) < 1024 ? QSCALE : 1.0f;
#pragma unroll
    for (int k = 0; k < 4; ++k)
      tile[ty + 8 * k][tx] =
          f32_to_bf16(Wqkv[(size_t)(rb + ty + 8 * k) * 3072 + cb + tx] * s);
    __syncthreads();
#pragma unroll
    for (int k = 0; k < 4; ++k)
      wqkvT[(size_t)(cb + ty + 8 * k) * 1024 + rb + tx] = tile[tx][ty + 8 * k];
  } else {
    int tb = bid - 5120;                 // 32 x 32 tiles
    int cb = (tb & 31) * 32, rb = (tb >> 5) * 32;
    int tx = t & 31, ty = t >> 5;
#pragma unroll
    for (int k = 0; k < 4; ++k)
      tile[ty + 8 * k][tx] =
          f32_to_bf16(Wout[(size_t)(rb + ty + 8 * k) * 1024 + cb + tx]);
    __syncthreads();
#pragma unroll
    for (int k = 0; k < 4; ++k)
      woutT[(size_t)(cb + ty + 8 * k) * 1024 + rb + tx] = tile[tx][ty + 8 * k];
  }
}

// ---------------------------------------------------------------------------
// GEMM core: C tile = A[M,K] * Bt[N,K]^T (+ fp32 bias). bf16 in, fp32 accum.
// TM x 128 tile, BK in {32,64}, double-buffered global_load_lds staging,
// single barrier per K-iter. LDS rows are XOR-chunk-swizzled so b128
// fragment reads span all bank quads (2-way residual aliasing = free):
//   BK=32: 4 chunks/row, key = (row>>1)&3;  BK=64: 8 chunks/row, key = row&7.
// ---------------------------------------------------------------------------
template <int TM, int BK>
__device__ __forceinline__ void stage_ab(
    const ushort* __restrict__ A, const ushort* __restrict__ Bt,
    int K, int mbase, int nbase, int kb,
    ushort* __restrict__ sA, ushort* __restrict__ sB,
    int w, int lrow, int gofs)
{
  constexpr int ROWS = (BK == 32) ? 16 : 8;  // rows per wave-op (1KB)
#pragma unroll
  for (int r = 0; r < TM / (ROWS * 4); ++r) {
    int rb = w * (TM / 4) + r * ROWS;
    load16_to_lds(&A[(size_t)(mbase + rb + lrow) * K + kb + gofs], &sA[rb * BK]);
  }
#pragma unroll
  for (int r = 0; r < 128 / (ROWS * 4); ++r) {
    int rb = w * 32 + r * ROWS;
    load16_to_lds(&Bt[(size_t)(nbase + rb + lrow) * K + kb + gofs], &sB[rb * BK]);
  }
}

template <int TM, int BK, typename TC>
__device__ __forceinline__ void gemm_core(
    const ushort* __restrict__ A, const ushort* __restrict__ Bt,
    const float* __restrict__ bias, TC* __restrict__ C,
    int N, int K, int mbase, int nbase,
    ushort* __restrict__ sA0, ushort* __restrict__ sB0,
    ushort* __restrict__ sA1, ushort* __restrict__ sB1)
{
  constexpr int MT = TM / 32;
  const int t = threadIdx.x;
  const int lane = t & 63, w = t >> 6;
  const int quad = lane >> 4, l16 = lane & 15;
  const int wr = w >> 1, wc = w & 1;
  // staging lane mapping + global-side swizzle
  const int lrow = (BK == 32) ? (lane >> 2) : (lane >> 3);
  const int gofs = (BK == 32)
      ? (((lane & 3) ^ ((lane >> 3) & 3)) * 8)
      : (((lane & 7) ^ (lane >> 3)) * 8);
  // read-side swizzle key
  const int rswz = (BK == 32) ? ((l16 >> 1) & 3) : (l16 & 7);

  f32x4 acc[MT][4];
#pragma unroll
  for (int i = 0; i < MT; ++i)
#pragma unroll
    for (int j = 0; j < 4; ++j)
      acc[i][j] = (f32x4){0.f, 0.f, 0.f, 0.f};

  stage_ab<TM, BK>(A, Bt, K, mbase, nbase, 0, sA0, sB0, w, lrow, gofs);

  for (int kb = 0; kb < K; kb += BK) {
    const bool odd = (kb / BK) & 1;
    ushort* sA = odd ? sA1 : sA0;
    ushort* sB = odd ? sB1 : sB0;
    ushort* pA = odd ? sA0 : sA1;
    ushort* pB = odd ? sB0 : sB1;
    __syncthreads();  // cur buffer staged; prefetch below overlaps compute
    if (kb + BK < K)
      stage_ab<TM, BK>(A, Bt, K, mbase, nbase, kb + BK, pA, pB, w, lrow, gofs);

#pragma unroll
    for (int c = 0; c < BK / 32; ++c) {
      bf16x8 af[MT], bfr[4];
#pragma unroll
      for (int mt = 0; mt < MT; ++mt)
        af[mt] = *(const bf16x8*)&sA[(wr * (TM / 2) + mt * 16 + l16) * BK +
                                     (((c * 4 + quad) ^ rswz) * 8)];
#pragma unroll
      for (int nt = 0; nt < 4; ++nt)
        bfr[nt] = *(const bf16x8*)&sB[(wc * 64 + nt * 16 + l16) * BK +
                                      (((c * 4 + quad) ^ rswz) * 8)];
#pragma unroll
      for (int mt = 0; mt < MT; ++mt)
#pragma unroll
        for (int nt = 0; nt < 4; ++nt)
          acc[mt][nt] = __builtin_amdgcn_mfma_f32_16x16x32_bf16(
              af[mt], bfr[nt], acc[mt][nt], 0, 0, 0);
    }
  }

#pragma unroll
  for (int mt = 0; mt < MT; ++mt) {
#pragma unroll
    for (int nt = 0; nt < 4; ++nt) {
      int col = nbase + wc * 64 + nt * 16 + l16;
      float bv = bias ? bias[col] : 0.f;
#pragma unroll
      for (int ri = 0; ri < 4; ++ri) {
        int row = mbase + wr * (TM / 2) + mt * 16 + quad * 4 + ri;
        float val = acc[mt][nt][ri] + bv;
        if constexpr (__is_same(TC, float))
          C[(size_t)row * N + col] = val;
        else
          C[(size_t)row * N + col] = f32_to_bf16(val);
      }
    }
  }
}

// blocks [0,512): qk = xb @ WqkvT[0:2048]^T       -> [4096][2048] bf16
// blocks [512,768): V^T = WqkvT[2048:] @ xb^T     -> [1024][4096] bf16
__global__ __launch_bounds__(256) void gemm_qkvt(
    const ushort* __restrict__ xb, const ushort* __restrict__ wqkvT,
    ushort* __restrict__ qk, ushort* __restrict__ vtbuf)
{
  __shared__ ushort sA0[128 * 32], sB0[128 * 32];
  __shared__ ushort sA1[128 * 32], sB1[128 * 32];
  const int bid = blockIdx.x;
  if (bid < 512) {
    gemm_core<128, 32, ushort>(xb, wqkvT, nullptr, qk, 2048, 1024,
                               (bid >> 4) * 128, (bid & 15) * 128,
                               sA0, sB0, sA1, sB1);
  } else {
    const int id = bid - 512;
    gemm_core<128, 32, ushort>(wqkvT + (size_t)2048 * 1024, xb, nullptr, vtbuf,
                               4096, 1024, (id >> 5) * 128, (id & 31) * 128,
                               sA0, sB0, sA1, sB1);
  }
}

// out = attnb @ WoutT^T + b_out (fp32 store). 64x128 tiles -> 512 blocks.
__global__ __launch_bounds__(256) void gemm_out(
    const ushort* __restrict__ attnb, const ushort* __restrict__ woutT,
    const float* __restrict__ bias, float* __restrict__ out)
{
  __shared__ ushort sA0[64 * 64], sB0[128 * 64];
  __shared__ ushort sA1[64 * 64], sB1[128 * 64];
  const int bid = blockIdx.x;
  gemm_core<64, 64, float>(attnb, woutT, bias, out, 1024, 1024,
                           (bid >> 3) * 64, (bid & 7) * 128,
                           sA0, sB0, sA1, sB1);
}

// ---------------------------------------------------------------------------
// Flash attention, S^T formulation, no-max softmax (Q pre-scaled by
// scale*log2e). P transform C-layout -> A-operand via per-wave LDS buffer.
// l via ones-MFMA. K/V double-buffered via global_load_lds, single barrier
// per iteration. 4 waves x 32 q-rows = 128-row Q blocks. (Unchanged from R7.)
// ---------------------------------------------------------------------------
__device__ __forceinline__ void stage_kv(
    const ushort* __restrict__ qk, const ushort* __restrict__ vt,
    ushort* sKb, ushort* sVb, int b, int h, int kvbase,
    int w, int rowK, int csw)
{
#pragma unroll
  for (int g = 0; g < 2; ++g) {
    int rk = w * 16 + g * 8 + rowK;
    load16_to_lds(&qk[((size_t)(b * NS + kvbase + rk)) * 2048 + 1024 + h * 64 + csw],
                  &sKb[(w * 16 + g * 8) * 64]);
    load16_to_lds(&vt[((size_t)(h * 64 + rk)) * 4096 + b * 2048 + kvbase + csw],
                  &sVb[(w * 16 + g * 8) * 64]);
  }
}

__global__ __launch_bounds__(256) void attn_kernel(
    const ushort* __restrict__ qk, const ushort* __restrict__ vt,
    ushort* __restrict__ attn_out)
{
  __shared__ ushort sK[2][64 * 64];
  __shared__ ushort sV[2][64 * 64];
  __shared__ ushort sPt[4][32][72];

  const int t = threadIdx.x;
  const int lane = t & 63, w = t >> 6;
  const int quad = lane >> 4, l16 = lane & 15;
  const int bh = blockIdx.y, b = bh >> 4, h = bh & 15;
  const int qbase = blockIdx.x * 128;
  const int rowK = lane >> 3;
  const int csw = ((lane & 7) ^ rowK) * 8;
  const int swz = l16 & 7;

  bf16x8 qf[2][2];
#pragma unroll
  for (int is = 0; is < 2; ++is)
#pragma unroll
    for (int c = 0; c < 2; ++c)
      qf[is][c] = *(const bf16x8*)&qk[
          ((size_t)(b * NS + qbase + w * 32 + is * 16 + l16)) * 2048 +
          h * 64 + c * 32 + quad * 8];

  bf16x8 ones;
  { union { bf16x8 v; ushort s[8]; } ou;
#pragma unroll
    for (int i = 0; i < 8; ++i) ou.s[i] = 0x3F80;
    ones = ou.v; }

  unsigned amask[2][4][2];
#pragma unroll
  for (int is = 0; is < 2; ++is)
#pragma unroll
    for (int mt = 0; mt < 4; ++mt)
#pragma unroll
      for (int hf = 0; hf < 2; ++hf) {
        int r0 = hf * 2, r1 = hf * 2 + 1;
        int base = is * 16 + l16 - mt * 16 - quad * 4;
        unsigned m = 0xFFFFFFFFu;
        if (((base - r0) & 31) == 0) m &= 0xFFFF0000u;
        if (((base - r1) & 31) == 0) m &= 0x0000FFFFu;
        amask[is][mt][hf] = m;
      }

  const int ib64 = (qbase + w * 32) >> 6;

  f32x4 oacc[2][4];
#pragma unroll
  for (int is = 0; is < 2; ++is)
#pragma unroll
    for (int dt = 0; dt < 4; ++dt) oacc[is][dt] = (f32x4){0.f, 0.f, 0.f, 0.f};
  f32x4 lsum[2];
  lsum[0] = (f32x4){0.f, 0.f, 0.f, 0.f};
  lsum[1] = (f32x4){0.f, 0.f, 0.f, 0.f};

  stage_kv(qk, vt, sK[0], sV[0], b, h, 0, w, rowK, csw);

  for (int kb = 0; kb < NS / 64; ++kb) {
    const int cur = kb & 1;
    const int kvbase = kb * 64;
    __syncthreads();
    if (kb < NS / 64 - 1)
      stage_kv(qk, vt, sK[cur ^ 1], sV[cur ^ 1], b, h, kvbase + 64, w, rowK, csw);

    const ushort* K = sK[cur];
    const ushort* V = sV[cur];

    f32x4 st[2][4];
#pragma unroll
    for (int is = 0; is < 2; ++is)
#pragma unroll
      for (int mt = 0; mt < 4; ++mt) st[is][mt] = (f32x4){0.f, 0.f, 0.f, 0.f};
#pragma unroll
    for (int mt = 0; mt < 4; ++mt)
#pragma unroll
      for (int c = 0; c < 2; ++c) {
        bf16x8 kf = *(const bf16x8*)&K[(mt * 16 + l16) * 64 +
                                       (((c * 4 + quad) ^ swz) * 8)];
        st[0][mt] = __builtin_amdgcn_mfma_f32_16x16x32_bf16(
            kf, qf[0][c], st[0][mt], 0, 0, 0);
        st[1][mt] = __builtin_amdgcn_mfma_f32_16x16x32_bf16(
            kf, qf[1][c], st[1][mt], 0, 0, 0);
      }

    if (kb < ib64) {
#pragma unroll
      for (int is = 0; is < 2; ++is)
#pragma unroll
        for (int mt = 0; mt < 4; ++mt) {
          unsigned lo = pack_bf16(EXP2F(st[is][mt][0]), EXP2F(st[is][mt][1])) &
                        amask[is][mt][0];
          unsigned hi = pack_bf16(EXP2F(st[is][mt][2]), EXP2F(st[is][mt][3])) &
                        amask[is][mt][1];
          *(uint2*)&sPt[w][is * 16 + l16][mt * 16 + quad * 4] =
              make_uint2(lo, hi);
        }
    } else if (kb > ib64) {
#pragma unroll
      for (int is = 0; is < 2; ++is)
#pragma unroll
        for (int mt = 0; mt < 4; ++mt) {
          unsigned lo = pack_bf16(EXP2F(st[is][mt][0]), EXP2F(st[is][mt][1]));
          unsigned hi = pack_bf16(EXP2F(st[is][mt][2]), EXP2F(st[is][mt][3]));
          *(uint2*)&sPt[w][is * 16 + l16][mt * 16 + quad * 4] =
              make_uint2(lo, hi);
        }
    } else {
#pragma unroll
      for (int is = 0; is < 2; ++is) {
        int irow = qbase + w * 32 + is * 16 + l16;
#pragma unroll
        for (int mt = 0; mt < 4; ++mt) {
          float p[4];
#pragma unroll
          for (int ri = 0; ri < 4; ++ri) {
            int j = kvbase + mt * 16 + quad * 4 + ri;
            p[ri] = EXP2F(st[is][mt][ri]);
            unsigned du = (unsigned)(irow - j);
            if ((du & 0x8000001Fu) == 0u) p[ri] = 0.f;
          }
          unsigned lo = pack_bf16(p[0], p[1]);
          unsigned hi = pack_bf16(p[2], p[3]);
          *(uint2*)&sPt[w][is * 16 + l16][mt * 16 + quad * 4] =
              make_uint2(lo, hi);
        }
      }
    }

#pragma unroll
    for (int c2 = 0; c2 < 2; ++c2) {
      bf16x8 vf[4];
#pragma unroll
      for (int dt = 0; dt < 4; ++dt)
        vf[dt] = *(const bf16x8*)&V[(dt * 16 + l16) * 64 +
                                    (((c2 * 4 + quad) ^ swz) * 8)];
#pragma unroll
      for (int is = 0; is < 2; ++is) {
        bf16x8 pf = *(const bf16x8*)&sPt[w][is * 16 + l16][c2 * 32 + quad * 8];
        lsum[is] = __builtin_amdgcn_mfma_f32_16x16x32_bf16(
            pf, ones, lsum[is], 0, 0, 0);
#pragma unroll
        for (int dt = 0; dt < 4; ++dt)
          oacc[is][dt] = __builtin_amdgcn_mfma_f32_16x16x32_bf16(
              pf, vf[dt], oacc[is][dt], 0, 0, 0);
      }
    }
  }

#pragma unroll
  for (int is = 0; is < 2; ++is)
#pragma unroll
    for (int ri = 0; ri < 4; ++ri) {
      float inv = __builtin_amdgcn_rcpf(lsum[is][ri]);
      int ig = qbase + w * 32 + is * 16 + quad * 4 + ri;
#pragma unroll
      for (int dt = 0; dt < 4; ++dt)
        attn_out[(size_t)(b * NS + ig) * 1024 + h * 64 + dt * 16 + l16] =
            f32_to_bf16(oacc[is][dt][ri] * inv);
    }
}

// ---------------------------------------------------------------------------
extern "C" void kernel_launch(void* const* d_in, const int* in_sizes, int n_in,
                              void* d_out, int out_size, void* d_ws, size_t ws_size,
                              hipStream_t stream) {
  const float* x    = (const float*)d_in[0];  // [2,2048,1024] fp32
  const float* Wqkv = (const float*)d_in[1];  // [1024,3072]
  const float* Wout = (const float*)d_in[2];  // [1024,1024]
  const float* bout = (const float*)d_in[3];  // [1024]
  float* out = (float*)d_out;                 // [2,2048,1024] fp32

  ushort* qk    = (ushort*)d_ws;                 // 4096*2048 = 16 MiB
  ushort* vt    = qk + (size_t)4096 * 2048;      // 1024*4096 = 8 MiB
  ushort* xb    = vt + (size_t)1024 * 4096;      // 8 MiB (reused as attnb)
  ushort* wqkvT = xb + (size_t)4096 * 1024;      // 3072*1024 = 6 MiB
  ushort* woutT = wqkvT + (size_t)3072 * 1024;   // 1024*1024 = 2 MiB
  ushort* attnb = xb;

  // prep: x->bf16 + W_qkv^T (Q cols pre-scaled) + W_out^T
  prep<<<6144, 256, 0, stream>>>(x, Wqkv, Wout, xb, wqkvT, woutT);
  // qk [4096][2048] + V^T [1024][4096], one launch (768 blocks)
  gemm_qkvt<<<768, 256, 0, stream>>>(xb, wqkvT, qk, vt);
  // attention
  attn_kernel<<<dim3(NS / 128, 32), 256, 0, stream>>>(qk, vt, attnb);
  // out = attnb @ WoutT^T + b_out (fp32), 64x128 tiles
  gemm_out<<<512, 256, 0, stream>>>(attnb, woutT, bout, out);
}

// Round 10
// 174.639 us; speedup vs baseline: 1.2670x; 1.0780x over previous
//
#include <hip/hip_runtime.h>

typedef __attribute__((ext_vector_type(8))) short bf16x8;
typedef __attribute__((ext_vector_type(4))) float f32x4;

#if __has_builtin(__builtin_amdgcn_exp2f)
#define EXP2F(x) __builtin_amdgcn_exp2f(x)
#else
extern "C" __device__ float __ocml_native_exp2_f32(float);
#define EXP2F(x) __ocml_native_exp2_f32(x)
#endif

// qscale = log2(e) / 32, baked into Q columns of W_qkv
#define QSCALE 0.04508422002778011f
#define NS 2048

__device__ __forceinline__ ushort f32_to_bf16(float f) {
  union { float f; unsigned u; } x; x.f = f;
  unsigned r = x.u + 0x7fffu + ((x.u >> 16) & 1u);
  return (ushort)(r >> 16);
}

// pack two f32 -> one dword of two bf16 (lo = f0, hi = f1)
__device__ __forceinline__ unsigned pack_bf16(float f0, float f1) {
  union { float f; unsigned u; } a, b;
  a.f = f0; b.f = f1;
  return __builtin_amdgcn_perm(b.u + 0x8000u, a.u + 0x8000u, 0x07060302u);
}

// async global->LDS, 16B per lane; lds base must be wave-uniform
__device__ __forceinline__ void load16_to_lds(const void* g, void* l) {
  __builtin_amdgcn_global_load_lds(
      (const __attribute__((address_space(1))) unsigned int*)(
          reinterpret_cast<uintptr_t>(g)),
      (__attribute__((address_space(3))) unsigned int*)(
          reinterpret_cast<uintptr_t>(l)),
      16, 0, 0);
}

// ---------------------------------------------------------------------------
// prep: blocks [0,2048): convert x -> bf16 (8 elems/thread)
//       blocks [2048,5120): W_qkv^T -> wqkvT [3072][1024], Q cols scaled
//       blocks [5120,6144): W_out^T -> woutT [1024][1024]
// ---------------------------------------------------------------------------
__global__ __launch_bounds__(256) void prep(
    const float* __restrict__ x, const float* __restrict__ Wqkv,
    const float* __restrict__ Wout,
    ushort* __restrict__ xb, ushort* __restrict__ wqkvT,
    ushort* __restrict__ woutT)
{
  __shared__ ushort tile[32][33];
  const int bid = blockIdx.x, t = threadIdx.x;
  if (bid < 2048) {
    size_t i = (size_t)bid * 256 + t;
    const float4* p = (const float4*)(x + i * 8);
    float4 a = p[0], b = p[1];
    union { uint4 v; ushort s[8]; } u;
    u.s[0] = f32_to_bf16(a.x); u.s[1] = f32_to_bf16(a.y);
    u.s[2] = f32_to_bf16(a.z); u.s[3] = f32_to_bf16(a.w);
    u.s[4] = f32_to_bf16(b.x); u.s[5] = f32_to_bf16(b.y);
    u.s[6] = f32_to_bf16(b.z); u.s[7] = f32_to_bf16(b.w);
    *(uint4*)(xb + i * 8) = u.v;
  } else if (bid < 5120) {
    int tb = bid - 2048;                 // 96 col-tiles x 32 row-tiles
    int cb = (tb % 96) * 32, rb = (tb / 96) * 32;
    int tx = t & 31, ty = t >> 5;
    float s = (cb + tx) < 1024 ? QSCALE : 1.0f;
#pragma unroll
    for (int k = 0; k < 4; ++k)
      tile[ty + 8 * k][tx] =
          f32_to_bf16(Wqkv[(size_t)(rb + ty + 8 * k) * 3072 + cb + tx] * s);
    __syncthreads();
#pragma unroll
    for (int k = 0; k < 4; ++k)
      wqkvT[(size_t)(cb + ty + 8 * k) * 1024 + rb + tx] = tile[tx][ty + 8 * k];
  } else {
    int tb = bid - 5120;                 // 32 x 32 tiles
    int cb = (tb & 31) * 32, rb = (tb >> 5) * 32;
    int tx = t & 31, ty = t >> 5;
#pragma unroll
    for (int k = 0; k < 4; ++k)
      tile[ty + 8 * k][tx] =
          f32_to_bf16(Wout[(size_t)(rb + ty + 8 * k) * 1024 + cb + tx]);
    __syncthreads();
#pragma unroll
    for (int k = 0; k < 4; ++k)
      woutT[(size_t)(cb + ty + 8 * k) * 1024 + rb + tx] = tile[tx][ty + 8 * k];
  }
}

// ---------------------------------------------------------------------------
// GEMM core: C tile = A[M,K] * Bt[N,K]^T (+ fp32 bias). bf16 in, fp32 accum.
// TM x 128 tile, BK in {32,64}, double-buffered global_load_lds staging,
// single barrier per K-iter. LDS rows XOR-chunk-swizzled (conflict-free b128).
// ---------------------------------------------------------------------------
template <int TM, int BK>
__device__ __forceinline__ void stage_ab(
    const ushort* __restrict__ A, const ushort* __restrict__ Bt,
    int K, int mbase, int nbase, int kb,
    ushort* __restrict__ sA, ushort* __restrict__ sB,
    int w, int lrow, int gofs)
{
  constexpr int ROWS = (BK == 32) ? 16 : 8;  // rows per wave-op (1KB)
#pragma unroll
  for (int r = 0; r < TM / (ROWS * 4); ++r) {
    int rb = w * (TM / 4) + r * ROWS;
    load16_to_lds(&A[(size_t)(mbase + rb + lrow) * K + kb + gofs], &sA[rb * BK]);
  }
#pragma unroll
  for (int r = 0; r < 128 / (ROWS * 4); ++r) {
    int rb = w * 32 + r * ROWS;
    load16_to_lds(&Bt[(size_t)(nbase + rb + lrow) * K + kb + gofs], &sB[rb * BK]);
  }
}

template <int TM, int BK, typename TC>
__device__ __forceinline__ void gemm_core(
    const ushort* __restrict__ A, const ushort* __restrict__ Bt,
    const float* __restrict__ bias, TC* __restrict__ C,
    int N, int K, int mbase, int nbase,
    ushort* __restrict__ sA0, ushort* __restrict__ sB0,
    ushort* __restrict__ sA1, ushort* __restrict__ sB1)
{
  constexpr int MT = TM / 32;
  const int t = threadIdx.x;
  const int lane = t & 63, w = t >> 6;
  const int quad = lane >> 4, l16 = lane & 15;
  const int wr = w >> 1, wc = w & 1;
  const int lrow = (BK == 32) ? (lane >> 2) : (lane >> 3);
  const int gofs = (BK == 32)
      ? (((lane & 3) ^ ((lane >> 3) & 3)) * 8)
      : (((lane & 7) ^ (lane >> 3)) * 8);
  const int rswz = (BK == 32) ? ((l16 >> 1) & 3) : (l16 & 7);

  f32x4 acc[MT][4];
#pragma unroll
  for (int i = 0; i < MT; ++i)
#pragma unroll
    for (int j = 0; j < 4; ++j)
      acc[i][j] = (f32x4){0.f, 0.f, 0.f, 0.f};

  stage_ab<TM, BK>(A, Bt, K, mbase, nbase, 0, sA0, sB0, w, lrow, gofs);

  for (int kb = 0; kb < K; kb += BK) {
    const bool odd = (kb / BK) & 1;
    ushort* sA = odd ? sA1 : sA0;
    ushort* sB = odd ? sB1 : sB0;
    ushort* pA = odd ? sA0 : sA1;
    ushort* pB = odd ? sB0 : sB1;
    __syncthreads();
    if (kb + BK < K)
      stage_ab<TM, BK>(A, Bt, K, mbase, nbase, kb + BK, pA, pB, w, lrow, gofs);

#pragma unroll
    for (int c = 0; c < BK / 32; ++c) {
      bf16x8 af[MT], bfr[4];
#pragma unroll
      for (int mt = 0; mt < MT; ++mt)
        af[mt] = *(const bf16x8*)&sA[(wr * (TM / 2) + mt * 16 + l16) * BK +
                                     (((c * 4 + quad) ^ rswz) * 8)];
#pragma unroll
      for (int nt = 0; nt < 4; ++nt)
        bfr[nt] = *(const bf16x8*)&sB[(wc * 64 + nt * 16 + l16) * BK +
                                      (((c * 4 + quad) ^ rswz) * 8)];
#pragma unroll
      for (int mt = 0; mt < MT; ++mt)
#pragma unroll
        for (int nt = 0; nt < 4; ++nt)
          acc[mt][nt] = __builtin_amdgcn_mfma_f32_16x16x32_bf16(
              af[mt], bfr[nt], acc[mt][nt], 0, 0, 0);
    }
  }

#pragma unroll
  for (int mt = 0; mt < MT; ++mt) {
#pragma unroll
    for (int nt = 0; nt < 4; ++nt) {
      int col = nbase + wc * 64 + nt * 16 + l16;
      float bv = bias ? bias[col] : 0.f;
#pragma unroll
      for (int ri = 0; ri < 4; ++ri) {
        int row = mbase + wr * (TM / 2) + mt * 16 + quad * 4 + ri;
        float val = acc[mt][nt][ri] + bv;
        if constexpr (__is_same(TC, float))
          C[(size_t)row * N + col] = val;
        else
          C[(size_t)row * N + col] = f32_to_bf16(val);
      }
    }
  }
}

// blocks [0,512): qk = xb @ WqkvT[0:2048]^T       -> [4096][2048] bf16
// blocks [512,768): V^T = WqkvT[2048:] @ xb^T     -> [1024][4096] bf16
// XCD swizzle: blocks on one XCD (bid%8) share a small set of A m-panels.
__global__ __launch_bounds__(256, 3) void gemm_qkvt(
    const ushort* __restrict__ xb, const ushort* __restrict__ wqkvT,
    ushort* __restrict__ qk, ushort* __restrict__ vtbuf)
{
  __shared__ ushort sA0[128 * 32], sB0[128 * 32];
  __shared__ ushort sA1[128 * 32], sB1[128 * 32];
  const int bid = blockIdx.x;
  if (bid < 512) {
    int j = bid >> 3;                       // 0..63
    int m = (bid & 7) * 4 + (j & 3);        // 0..31
    int n = j >> 2;                         // 0..15
    gemm_core<128, 32, ushort>(xb, wqkvT, nullptr, qk, 2048, 1024,
                               m * 128, n * 128, sA0, sB0, sA1, sB1);
  } else {
    const int id = bid - 512;               // 0..255: 8 m x 32 n
    gemm_core<128, 32, ushort>(wqkvT + (size_t)2048 * 1024, xb, nullptr, vtbuf,
                               4096, 1024, (id & 7) * 128, (id >> 3) * 128,
                               sA0, sB0, sA1, sB1);
  }
}

// out = attnb @ WoutT^T + b_out (fp32). 64x128 tiles -> 512 blocks (64m x 8n).
__global__ __launch_bounds__(256) void gemm_out(
    const ushort* __restrict__ attnb, const ushort* __restrict__ woutT,
    const float* __restrict__ bias, float* __restrict__ out)
{
  __shared__ ushort sA0[64 * 64], sB0[128 * 64];
  __shared__ ushort sA1[64 * 64], sB1[128 * 64];
  const int bid = blockIdx.x;
  int m = (bid & 7) * 8 + ((bid >> 3) & 7);  // 0..63
  int n = bid >> 6;                          // 0..7
  gemm_core<64, 64, float>(attnb, woutT, bias, out, 1024, 1024,
                           m * 64, n * 128, sA0, sB0, sA1, sB1);
}

// ---------------------------------------------------------------------------
// Flash attention, S^T formulation, no-max softmax (Q pre-scaled by
// scale*log2e). 512 threads: 8 waves x 16 q-rows = 128-row Q blocks ->
// 16 waves/CU (4/SIMD) for latency hiding; per-wave chains halved.
// P transform C-layout -> A-operand via per-wave LDS buffer. l via ones-MFMA.
// K/V double-buffered via global_load_lds, single barrier per iteration.
// FIX vs R9: pattern mask base must include (w&1)*16 -- with 16 q-rows/wave
// the dropped wave-uniform term w*16 is NOT a multiple of 32 for odd waves.
// ---------------------------------------------------------------------------
__device__ __forceinline__ void stage_kv(
    const ushort* __restrict__ qk, const ushort* __restrict__ vt,
    ushort* sKb, ushort* sVb, int b, int h, int kvbase,
    int w, int rowK, int csw)
{
  int rk = w * 8 + rowK;  // 8 waves x 8 rows = 64
  load16_to_lds(&qk[((size_t)(b * NS + kvbase + rk)) * 2048 + 1024 + h * 64 + csw],
                &sKb[(w * 8) * 64]);
  load16_to_lds(&vt[((size_t)(h * 64 + rk)) * 4096 + b * 2048 + kvbase + csw],
                &sVb[(w * 8) * 64]);
}

__global__ __launch_bounds__(512, 4) void attn_kernel(
    const ushort* __restrict__ qk, const ushort* __restrict__ vt,
    ushort* __restrict__ attn_out)
{
  __shared__ ushort sK[2][64 * 64];  // [kv][d] chunk-swizzled, double-buffered
  __shared__ ushort sV[2][64 * 64];  // [d][kv] chunk-swizzled
  __shared__ ushort sPt[8][16][72];  // per-wave [i][j], +8 pad

  const int t = threadIdx.x;
  const int lane = t & 63, w = t >> 6;  // w 0..7
  const int quad = lane >> 4, l16 = lane & 15;
  const int bh = blockIdx.y, b = bh >> 4, h = bh & 15;
  const int qbase = blockIdx.x * 128;
  const int rowK = lane >> 3;
  const int csw = ((lane & 7) ^ rowK) * 8;
  const int swz = l16 & 7;

  // Q fragments (B-operand): n=l16 -> i (wave's 16 rows), k=quad*8+j -> d
  bf16x8 qf[2];
#pragma unroll
  for (int c = 0; c < 2; ++c)
    qf[c] = *(const bf16x8*)&qk[
        ((size_t)(b * NS + qbase + w * 16 + l16)) * 2048 +
        h * 64 + c * 32 + quad * 8];

  bf16x8 ones;
  { union { bf16x8 v; ushort s[8]; } ou;
#pragma unroll
    for (int i = 0; i < 8; ++i) ou.s[i] = 0x3F80;
    ones = ou.v; }

  // kb-invariant pattern masks: masked <=> (i-j) % 32 == 0.
  // i = qbase + w*16 + l16; j = kvbase + mt*16 + quad*4 + ri.
  // qbase%128==0, kvbase%64==0 drop mod 32; w*16 does NOT -> keep (w&1)*16.
  unsigned amask[4][2];
#pragma unroll
  for (int mt = 0; mt < 4; ++mt)
#pragma unroll
    for (int hf = 0; hf < 2; ++hf) {
      int r0 = hf * 2, r1 = hf * 2 + 1;
      int base = (w & 1) * 16 + l16 - mt * 16 - quad * 4;
      unsigned m = 0xFFFFFFFFu;
      if (((base - r0) & 31) == 0) m &= 0xFFFF0000u;
      if (((base - r1) & 31) == 0) m &= 0x0000FFFFu;
      amask[mt][hf] = m;
    }

  const int ib64 = (qbase + w * 16) >> 6;  // wave-uniform boundary kv-tile

  f32x4 oacc[4];
#pragma unroll
  for (int dt = 0; dt < 4; ++dt) oacc[dt] = (f32x4){0.f, 0.f, 0.f, 0.f};
  f32x4 lsum = (f32x4){0.f, 0.f, 0.f, 0.f};

  stage_kv(qk, vt, sK[0], sV[0], b, h, 0, w, rowK, csw);

  for (int kb = 0; kb < NS / 64; ++kb) {
    const int cur = kb & 1;
    const int kvbase = kb * 64;
    __syncthreads();  // buf[cur] staged; prefetch below overlaps compute
    if (kb < NS / 64 - 1)
      stage_kv(qk, vt, sK[cur ^ 1], sV[cur ^ 1], b, h, kvbase + 64, w, rowK, csw);

    const ushort* K = sK[cur];
    const ushort* V = sV[cur];

    // S^T = K Q^T : lane holds j = mt*16 + quad*4 + ri, i = l16
    f32x4 st[4];
#pragma unroll
    for (int mt = 0; mt < 4; ++mt) st[mt] = (f32x4){0.f, 0.f, 0.f, 0.f};
#pragma unroll
    for (int mt = 0; mt < 4; ++mt)
#pragma unroll
      for (int c = 0; c < 2; ++c) {
        bf16x8 kf = *(const bf16x8*)&K[(mt * 16 + l16) * 64 +
                                       (((c * 4 + quad) ^ swz) * 8)];
        st[mt] = __builtin_amdgcn_mfma_f32_16x16x32_bf16(
            kf, qf[c], st[mt], 0, 0, 0);
      }

    // exp2 + mask + pack pairs -> sPt (C-layout -> A-layout transform)
    if (kb < ib64) {  // fully past diagonal: pattern mask
#pragma unroll
      for (int mt = 0; mt < 4; ++mt) {
        unsigned lo = pack_bf16(EXP2F(st[mt][0]), EXP2F(st[mt][1])) &
                      amask[mt][0];
        unsigned hi = pack_bf16(EXP2F(st[mt][2]), EXP2F(st[mt][3])) &
                      amask[mt][1];
        *(uint2*)&sPt[w][l16][mt * 16 + quad * 4] = make_uint2(lo, hi);
      }
    } else if (kb > ib64) {  // above diagonal: no mask
#pragma unroll
      for (int mt = 0; mt < 4; ++mt) {
        unsigned lo = pack_bf16(EXP2F(st[mt][0]), EXP2F(st[mt][1]));
        unsigned hi = pack_bf16(EXP2F(st[mt][2]), EXP2F(st[mt][3]));
        *(uint2*)&sPt[w][l16][mt * 16 + quad * 4] = make_uint2(lo, hi);
      }
    } else {  // boundary tile: full per-element test
      int irow = qbase + w * 16 + l16;
#pragma unroll
      for (int mt = 0; mt < 4; ++mt) {
        float p[4];
#pragma unroll
        for (int ri = 0; ri < 4; ++ri) {
          int j = kvbase + mt * 16 + quad * 4 + ri;
          p[ri] = EXP2F(st[mt][ri]);
          unsigned du = (unsigned)(irow - j);
          if ((du & 0x8000001Fu) == 0u) p[ri] = 0.f;
        }
        unsigned lo = pack_bf16(p[0], p[1]);
        unsigned hi = pack_bf16(p[2], p[3]);
        *(uint2*)&sPt[w][l16][mt * 16 + quad * 4] = make_uint2(lo, hi);
      }
    }

    // O += P V ; l += P * ones (P read back in A-operand layout, wave-local)
#pragma unroll
    for (int c2 = 0; c2 < 2; ++c2) {
      bf16x8 pf = *(const bf16x8*)&sPt[w][l16][c2 * 32 + quad * 8];
      lsum = __builtin_amdgcn_mfma_f32_16x16x32_bf16(pf, ones, lsum, 0, 0, 0);
#pragma unroll
      for (int dt = 0; dt < 4; ++dt) {
        bf16x8 vf = *(const bf16x8*)&V[(dt * 16 + l16) * 64 +
                                       (((c2 * 4 + quad) ^ swz) * 8)];
        oacc[dt] = __builtin_amdgcn_mfma_f32_16x16x32_bf16(
            pf, vf, oacc[dt], 0, 0, 0);
      }
    }
  }

  // epilogue: O / l   (lane holds i = quad*4 + ri, d = dt*16 + l16)
#pragma unroll
  for (int ri = 0; ri < 4; ++ri) {
    float inv = __builtin_amdgcn_rcpf(lsum[ri]);
    int ig = qbase + w * 16 + quad * 4 + ri;
#pragma unroll
    for (int dt = 0; dt < 4; ++dt)
      attn_out[(size_t)(b * NS + ig) * 1024 + h * 64 + dt * 16 + l16] =
          f32_to_bf16(oacc[dt][ri] * inv);
  }
}

// ---------------------------------------------------------------------------
extern "C" void kernel_launch(void* const* d_in, const int* in_sizes, int n_in,
                              void* d_out, int out_size, void* d_ws, size_t ws_size,
                              hipStream_t stream) {
  const float* x    = (const float*)d_in[0];  // [2,2048,1024] fp32
  const float* Wqkv = (const float*)d_in[1];  // [1024,3072]
  const float* Wout = (const float*)d_in[2];  // [1024,1024]
  const float* bout = (const float*)d_in[3];  // [1024]
  float* out = (float*)d_out;                 // [2,2048,1024] fp32

  ushort* qk    = (ushort*)d_ws;                 // 4096*2048 = 16 MiB
  ushort* vt    = qk + (size_t)4096 * 2048;      // 1024*4096 = 8 MiB
  ushort* xb    = vt + (size_t)1024 * 4096;      // 8 MiB (reused as attnb)
  ushort* wqkvT = xb + (size_t)4096 * 1024;      // 3072*1024 = 6 MiB
  ushort* woutT = wqkvT + (size_t)3072 * 1024;   // 1024*1024 = 2 MiB
  ushort* attnb = xb;

  // prep: x->bf16 + W_qkv^T (Q cols pre-scaled) + W_out^T
  prep<<<6144, 256, 0, stream>>>(x, Wqkv, Wout, xb, wqkvT, woutT);
  // qk [4096][2048] + V^T [1024][4096], one launch (768 blocks, XCD-swizzled)
  gemm_qkvt<<<768, 256, 0, stream>>>(xb, wqkvT, qk, vt);
  // attention (512 threads: 8 waves x 16 q-rows)
  attn_kernel<<<dim3(NS / 128, 32), 512, 0, stream>>>(qk, vt, attnb);
  // out = attnb @ WoutT^T + b_out (fp32), 64x128 tiles, XCD-swizzled
  gemm_out<<<512, 256, 0, stream>>>(attnb, woutT, bout, out);
}